// Round 1
// baseline (130.565 us; speedup 1.0000x reference)
//
#include <hip/hip_runtime.h>

#define T_SEQ 4096
#define C_DIM 1024
#define HD 64
#define NB 4

typedef __attribute__((ext_vector_type(8))) __bf16 bf16x8;
typedef __attribute__((ext_vector_type(8))) unsigned short us8;
typedef __attribute__((ext_vector_type(4))) unsigned short us4;
typedef __attribute__((ext_vector_type(4))) float f32x4;

// 0.125 (1/sqrt(64)) * log2(e): fold softmax scale + base-2 conversion into q
#define QSCALE 0.18033688011112042f

__device__ __forceinline__ unsigned short f2bf(float f) {
    union { float f; unsigned u; } x; x.f = f;
    unsigned r = x.u + 0x7FFFu + ((x.u >> 16) & 1u);   // RNE
    return (unsigned short)(r >> 16);
}

// ---------------- K0: W[1024][64] f32 -> W^T[192][1024] bf16 ----------------
__global__ __launch_bounds__(256) void k_wtrans(const float* __restrict__ Wq,
                                                const float* __restrict__ Wk,
                                                const float* __restrict__ Wv,
                                                unsigned short* __restrict__ wt_g) {
    __shared__ unsigned short tile[64][72];
    const int bx = blockIdx.x;
    const int which = bx >> 4;          // 0..2
    const int k0 = (bx & 15) * 64;
    const float* W = (which == 0) ? Wq : ((which == 1) ? Wk : Wv);
    const int t = threadIdx.x;
    {
        const int r = t >> 2, c0 = (t & 3) * 16;
        const float4* src = reinterpret_cast<const float4*>(W + (k0 + r) * HD + c0);
        #pragma unroll
        for (int i = 0; i < 4; ++i) {
            float4 v = src[i];
            tile[r][c0 + 4 * i + 0] = f2bf(v.x);
            tile[r][c0 + 4 * i + 1] = f2bf(v.y);
            tile[r][c0 + 4 * i + 2] = f2bf(v.z);
            tile[r][c0 + 4 * i + 3] = f2bf(v.w);
        }
    }
    __syncthreads();
    {
        const int n = t >> 2, kc0 = (t & 3) * 16;
        alignas(16) unsigned short o[16];
        #pragma unroll
        for (int i = 0; i < 16; ++i) o[i] = tile[kc0 + i][n];
        unsigned short* dst = wt_g + (size_t)(which * 64 + n) * 1024 + k0 + kc0;
        *reinterpret_cast<us8*>(dst)     = *reinterpret_cast<const us8*>(&o[0]);
        *reinterpret_cast<us8*>(dst + 8) = *reinterpret_cast<const us8*>(&o[8]);
    }
}

// ---------------- K1: q,k,v projections (MFMA, computes (xW)^T) -------------
// out: qs[16384][64] bf16 (scaled), ks[16384][64] bf16, vt[4][64][4096] bf16
__global__ __launch_bounds__(256) void k_proj(const float* __restrict__ x,
                                              const unsigned short* __restrict__ wt_g,
                                              unsigned short* __restrict__ qs,
                                              unsigned short* __restrict__ ks,
                                              unsigned short* __restrict__ vt) {
    __shared__ unsigned short smem[18432];      // 36864 B
    unsigned short* xs = smem;                  // [64][72] bf16
    unsigned short* wt = smem + 64 * 72;        // [192][72] bf16
    const int tid = threadIdx.x;
    const int w = tid >> 6;
    const int lane = tid & 63;
    const int l15 = lane & 15, g = lane >> 4;
    const int m0 = blockIdx.x * 64;

    f32x4 acc[3][4];
    #pragma unroll
    for (int mf = 0; mf < 3; ++mf)
        #pragma unroll
        for (int nf = 0; nf < 4; ++nf)
            acc[mf][nf] = (f32x4){0.f, 0.f, 0.f, 0.f};

    const int sr = tid >> 2, sc0 = (tid & 3) * 16;

    for (int kk = 0; kk < 16; ++kk) {
        {   // stage x chunk [64 m][64 k] f32 -> bf16 LDS
            const float4* src = reinterpret_cast<const float4*>(
                x + (size_t)(m0 + sr) * C_DIM + kk * 64 + sc0);
            alignas(16) unsigned short tmp[16];
            #pragma unroll
            for (int i = 0; i < 4; ++i) {
                float4 v = src[i];
                tmp[4 * i + 0] = f2bf(v.x); tmp[4 * i + 1] = f2bf(v.y);
                tmp[4 * i + 2] = f2bf(v.z); tmp[4 * i + 3] = f2bf(v.w);
            }
            unsigned short* dst = xs + sr * 72 + sc0;
            *reinterpret_cast<us8*>(dst)     = *reinterpret_cast<const us8*>(&tmp[0]);
            *reinterpret_cast<us8*>(dst + 8) = *reinterpret_cast<const us8*>(&tmp[8]);
        }
        {   // stage W^T chunk [192 n][64 k] bf16
            #pragma unroll
            for (int u = 0; u < 6; ++u) {
                const int cidx = tid * 6 + u;           // 0..1535
                const int n = cidx >> 3, bb = cidx & 7;
                us8 v = *reinterpret_cast<const us8*>(wt_g + (size_t)n * 1024 + kk * 64 + bb * 8);
                *reinterpret_cast<us8*>(wt + n * 72 + bb * 8) = v;
            }
        }
        __syncthreads();
        #pragma unroll
        for (int ks2 = 0; ks2 < 2; ++ks2) {
            bf16x8 bfr[4];
            #pragma unroll
            for (int nf = 0; nf < 4; ++nf)
                bfr[nf] = *reinterpret_cast<const bf16x8*>(xs + (nf * 16 + l15) * 72 + ks2 * 32 + g * 8);
            #pragma unroll
            for (int mf = 0; mf < 3; ++mf) {
                bf16x8 afr = *reinterpret_cast<const bf16x8*>(
                    wt + ((3 * w + mf) * 16 + l15) * 72 + ks2 * 32 + g * 8);
                #pragma unroll
                for (int nf = 0; nf < 4; ++nf)
                    acc[mf][nf] = __builtin_amdgcn_mfma_f32_16x16x32_bf16(
                        afr, bfr[nf], acc[mf][nf], 0, 0, 0);
            }
        }
        __syncthreads();
    }
    // epilogue: C^T frags -> out_lds[64 m][208 n] bf16 (reuses smem)
    unsigned short* out_lds = smem;
    #pragma unroll
    for (int mf = 0; mf < 3; ++mf) {
        const int Mfr = 3 * w + mf;                    // 0..11 -> n = 16*Mfr..
        const float s = (Mfr < 4) ? QSCALE : 1.0f;     // scale q columns (n<64)
        #pragma unroll
        for (int nf = 0; nf < 4; ++nf) {
            us4 pk;
            #pragma unroll
            for (int r = 0; r < 4; ++r) pk[r] = f2bf(acc[mf][nf][r] * s);
            const int m = nf * 16 + l15;
            const int n = Mfr * 16 + 4 * g;
            *reinterpret_cast<us4*>(out_lds + m * 208 + n) = pk;
        }
    }
    __syncthreads();
    {
        const int m = sr, c0 = sc0;
        const size_t gm = (size_t)(m0 + m);
        // q (already scaled), k: row-major coalesced
        *reinterpret_cast<us8*>(qs + gm * 64 + c0)     = *reinterpret_cast<const us8*>(out_lds + m * 208 + c0);
        *reinterpret_cast<us8*>(qs + gm * 64 + c0 + 8) = *reinterpret_cast<const us8*>(out_lds + m * 208 + c0 + 8);
        *reinterpret_cast<us8*>(ks + gm * 64 + c0)     = *reinterpret_cast<const us8*>(out_lds + m * 208 + 64 + c0);
        *reinterpret_cast<us8*>(ks + gm * 64 + c0 + 8) = *reinterpret_cast<const us8*>(out_lds + m * 208 + 64 + c0 + 8);
        // v transposed: vt[b][d][t]
        const int n = sr;            // v col (d)
        const int mb = sc0;          // t offset within tile
        const int b = m0 >> 12;
        const int t0 = m0 & 4095;
        alignas(16) unsigned short tmp[16];
        #pragma unroll
        for (int i = 0; i < 16; ++i) tmp[i] = out_lds[(mb + i) * 208 + 128 + n];
        unsigned short* dst = vt + (size_t)(b * 64 + n) * T_SEQ + t0 + mb;
        *reinterpret_cast<us8*>(dst)     = *reinterpret_cast<const us8*>(&tmp[0]);
        *reinterpret_cast<us8*>(dst + 8) = *reinterpret_cast<const us8*>(&tmp[8]);
    }
}

// ---------------- K2: causal flash attention ----------------
// 4 waves x 16 q-rows, KVBLK=64; swapped QK^T (mfma(K,Q)) so softmax needs
// only shfl_xor(16/32); P^T through padded LDS feeds PV's B operand.
__global__ __launch_bounds__(256) void k_attn(const unsigned short* __restrict__ qs,
                                              const unsigned short* __restrict__ ks,
                                              const unsigned short* __restrict__ vt,
                                              float* __restrict__ out) {
    __shared__ unsigned short kt[64 * 72];
    __shared__ unsigned short vtile[64 * 72];
    __shared__ unsigned short p_lds[4][16 * 72];
    const int tid = threadIdx.x;
    const int w = tid >> 6, lane = tid & 63;
    const int l15 = lane & 15, g = lane >> 4;
    const int batch = blockIdx.x >> 6;
    const int qt = blockIdx.x & 63;
    const int q0 = qt * 64;
    const int qi = q0 + 16 * w + l15;              // this lane's q (within batch)
    const size_t qrow = (size_t)batch * T_SEQ + qi;

    bf16x8 qfrag[2];
    #pragma unroll
    for (int ks2 = 0; ks2 < 2; ++ks2)
        qfrag[ks2] = *reinterpret_cast<const bf16x8*>(qs + qrow * 64 + ks2 * 32 + g * 8);

    f32x4 accO[4];
    #pragma unroll
    for (int df = 0; df < 4; ++df) accO[df] = (f32x4){0.f, 0.f, 0.f, 0.f};
    float m_run = -1e30f, l_run = 0.f;

    const int sr = tid >> 2, sc0 = (tid & 3) * 16;
    const int nkv = qt + 1;
    for (int it = 0; it < nkv; ++it) {
        const int k0 = it * 64;
        {   // stage K rows + V^T rows
            const unsigned short* srck = ks + ((size_t)batch * T_SEQ + k0 + sr) * 64 + sc0;
            unsigned short* dk = kt + sr * 72 + sc0;
            *reinterpret_cast<us8*>(dk)     = *reinterpret_cast<const us8*>(srck);
            *reinterpret_cast<us8*>(dk + 8) = *reinterpret_cast<const us8*>(srck + 8);
            const unsigned short* srcv = vt + (size_t)(batch * 64 + sr) * T_SEQ + k0 + sc0;
            unsigned short* dv = vtile + sr * 72 + sc0;
            *reinterpret_cast<us8*>(dv)     = *reinterpret_cast<const us8*>(srcv);
            *reinterpret_cast<us8*>(dv + 8) = *reinterpret_cast<const us8*>(srcv + 8);
        }
        __syncthreads();
        // S^T[k][q] = K * Q^T : lane holds q=l15, k = k0 + 16*kf + 4*g + r
        f32x4 sfr[4];
        #pragma unroll
        for (int kf = 0; kf < 4; ++kf) sfr[kf] = (f32x4){0.f, 0.f, 0.f, 0.f};
        #pragma unroll
        for (int ks2 = 0; ks2 < 2; ++ks2) {
            #pragma unroll
            for (int kf = 0; kf < 4; ++kf) {
                bf16x8 a = *reinterpret_cast<const bf16x8*>(kt + (kf * 16 + l15) * 72 + ks2 * 32 + g * 8);
                sfr[kf] = __builtin_amdgcn_mfma_f32_16x16x32_bf16(a, qfrag[ks2], sfr[kf], 0, 0, 0);
            }
        }
        // causal mask (skip if whole tile is below this wave's rows)
        if (k0 + 63 > q0 + 16 * w) {
            #pragma unroll
            for (int kf = 0; kf < 4; ++kf) {
                #pragma unroll
                for (int r = 0; r < 4; ++r) {
                    const int kidx = k0 + kf * 16 + 4 * g + r;
                    if (kidx > qi) sfr[kf][r] = -1e30f;
                }
            }
        }
        // online softmax in exp2 domain (scale+log2e folded into q)
        float mx = -1e30f;
        #pragma unroll
        for (int kf = 0; kf < 4; ++kf)
            #pragma unroll
            for (int r = 0; r < 4; ++r) mx = fmaxf(mx, sfr[kf][r]);
        mx = fmaxf(mx, __shfl_xor(mx, 16, 64));
        mx = fmaxf(mx, __shfl_xor(mx, 32, 64));
        const float m_new = fmaxf(m_run, mx);
        const float alpha = exp2f(m_run - m_new);
        float psum = 0.f;
        alignas(8) unsigned short pb[4][4];
        #pragma unroll
        for (int kf = 0; kf < 4; ++kf) {
            #pragma unroll
            for (int r = 0; r < 4; ++r) {
                const float p = exp2f(sfr[kf][r] - m_new);
                psum += p;
                pb[kf][r] = f2bf(p);
            }
        }
        psum += __shfl_xor(psum, 16, 64);
        psum += __shfl_xor(psum, 32, 64);
        l_run = l_run * alpha + psum;
        m_run = m_new;
        #pragma unroll
        for (int df = 0; df < 4; ++df) accO[df] *= alpha;
        // P^T -> p_lds stored [q][k] (padded 72) so PV B-frag is contiguous
        unsigned short* pw = p_lds[w];
        #pragma unroll
        for (int kf = 0; kf < 4; ++kf)
            *reinterpret_cast<us4*>(pw + l15 * 72 + kf * 16 + 4 * g) =
                *reinterpret_cast<const us4*>(&pb[kf][0]);
        __syncthreads();
        // O^T[d][q] += V^T * P^T
        bf16x8 bp[2];
        #pragma unroll
        for (int ks2 = 0; ks2 < 2; ++ks2)
            bp[ks2] = *reinterpret_cast<const bf16x8*>(pw + l15 * 72 + ks2 * 32 + g * 8);
        #pragma unroll
        for (int df = 0; df < 4; ++df) {
            #pragma unroll
            for (int ks2 = 0; ks2 < 2; ++ks2) {
                bf16x8 a = *reinterpret_cast<const bf16x8*>(vtile + (df * 16 + l15) * 72 + ks2 * 32 + g * 8);
                accO[df] = __builtin_amdgcn_mfma_f32_16x16x32_bf16(a, bp[ks2], accO[df], 0, 0, 0);
            }
        }
        __syncthreads();
    }
    const float inv = 1.0f / l_run;
    #pragma unroll
    for (int df = 0; df < 4; ++df) {
        f32x4 o = accO[df] * inv;
        *reinterpret_cast<f32x4*>(out + qrow * 64 + df * 16 + 4 * g) = o;
    }
}

extern "C" void kernel_launch(void* const* d_in, const int* in_sizes, int n_in,
                              void* d_out, int out_size, void* d_ws, size_t ws_size,
                              hipStream_t stream) {
    (void)in_sizes; (void)n_in; (void)out_size; (void)ws_size;
    const float* x  = (const float*)d_in[0];
    const float* Wq = (const float*)d_in[1];
    const float* Wk = (const float*)d_in[2];
    const float* Wv = (const float*)d_in[3];
    float* out = (float*)d_out;
    unsigned short* ws = (unsigned short*)d_ws;
    unsigned short* wt_g = ws;                 // 3*64*1024        = 196608 elems
    unsigned short* qsb  = ws + 196608;        // 16384*64         = 1048576
    unsigned short* ksb  = qsb + 1048576;      // 16384*64
    unsigned short* vtb  = ksb + 1048576;      // 4*64*4096
    k_wtrans<<<dim3(48),  dim3(256), 0, stream>>>(Wq, Wk, Wv, wt_g);
    k_proj  <<<dim3(256), dim3(256), 0, stream>>>(x, wt_g, qsb, ksb, vtb);
    k_attn  <<<dim3(256), dim3(256), 0, stream>>>(qsb, ksb, vtb, out);
}

// Round 2
// 74.652 us; speedup vs baseline: 1.7490x; 1.7490x over previous
//
#include <hip/hip_runtime.h>

#define T_SEQ 4096
#define C_DIM 1024
#define HD 64

typedef __attribute__((ext_vector_type(8))) __bf16 bf16x8;
typedef __attribute__((ext_vector_type(8))) unsigned short us8;
typedef __attribute__((ext_vector_type(4))) unsigned short us4;
typedef __attribute__((ext_vector_type(4))) float f32x4;

// 0.125 (1/sqrt(64)) * log2(e): fold softmax scale + base-2 conversion into q
#define QSCALE 0.18033688011112042f

__device__ __forceinline__ unsigned short f2bf(float f) {
    union { float f; unsigned u; } x; x.f = f;
    unsigned r = x.u + 0x7FFFu + ((x.u >> 16) & 1u);   // RNE
    return (unsigned short)(r >> 16);
}

__device__ __forceinline__ us8 cvt8(float4 a, float4 b) {
    union { __bf16 h[8]; us8 v; } u;
    u.h[0] = (__bf16)a.x; u.h[1] = (__bf16)a.y; u.h[2] = (__bf16)a.z; u.h[3] = (__bf16)a.w;
    u.h[4] = (__bf16)b.x; u.h[5] = (__bf16)b.y; u.h[6] = (__bf16)b.z; u.h[7] = (__bf16)b.w;
    return u.v;
}

// ---------------- K0: W[1024][64] f32 -> W^T[192][1024] bf16 ----------------
__global__ __launch_bounds__(256) void k_wtrans(const float* __restrict__ Wq,
                                                const float* __restrict__ Wk,
                                                const float* __restrict__ Wv,
                                                unsigned short* __restrict__ wt_g) {
    __shared__ unsigned short tile[64][72];
    const int bx = blockIdx.x;
    const int which = bx >> 4;          // 0..2
    const int k0 = (bx & 15) * 64;
    const float* W = (which == 0) ? Wq : ((which == 1) ? Wk : Wv);
    const int t = threadIdx.x;
    {
        const int r = t >> 2, c0 = (t & 3) * 16;
        const float4* src = reinterpret_cast<const float4*>(W + (k0 + r) * HD + c0);
        #pragma unroll
        for (int i = 0; i < 4; ++i) {
            float4 v = src[i];
            tile[r][c0 + 4 * i + 0] = f2bf(v.x);
            tile[r][c0 + 4 * i + 1] = f2bf(v.y);
            tile[r][c0 + 4 * i + 2] = f2bf(v.z);
            tile[r][c0 + 4 * i + 3] = f2bf(v.w);
        }
    }
    __syncthreads();
    {
        const int n = t >> 2, kc0 = (t & 3) * 16;
        alignas(16) unsigned short o[16];
        #pragma unroll
        for (int i = 0; i < 16; ++i) o[i] = tile[kc0 + i][n];
        unsigned short* dst = wt_g + (size_t)(which * 64 + n) * 1024 + k0 + kc0;
        *reinterpret_cast<us8*>(dst)     = *reinterpret_cast<const us8*>(&o[0]);
        *reinterpret_cast<us8*>(dst + 8) = *reinterpret_cast<const us8*>(&o[8]);
    }
}

// ---------------- K1: q,k,v projections, BM=32, dbuf, 1 barrier/iter --------
// out: qs[16384][64] bf16 (scaled), ks[16384][64] bf16, vt[4][64][4096] bf16
__global__ __launch_bounds__(256) void k_proj(const float* __restrict__ x,
                                              const unsigned short* __restrict__ wt_g,
                                              unsigned short* __restrict__ qs,
                                              unsigned short* __restrict__ ksb,
                                              unsigned short* __restrict__ vt) {
    __shared__ unsigned short smem[6656];        // xs dbuf (2*2304) + out_lds (6656) union
    unsigned short* xs0 = smem;
    unsigned short* xs1 = smem + 2304;
    const int tid = threadIdx.x;
    const int w = tid >> 6, lane = tid & 63;
    const int l15 = lane & 15, g = lane >> 4;
    const int m0 = blockIdx.x * 32;
    const int sr = tid >> 3, sc0 = (tid & 7) * 8;
    const float* xrow = x + (size_t)(m0 + sr) * C_DIM + sc0;
    const unsigned short* wrow[3];
    #pragma unroll
    for (int mf = 0; mf < 3; ++mf)
        wrow[mf] = wt_g + (size_t)((3 * w + mf) * 16 + l15) * C_DIM + g * 8;

    f32x4 acc[3][2];
    #pragma unroll
    for (int mf = 0; mf < 3; ++mf)
        #pragma unroll
        for (int nf = 0; nf < 2; ++nf)
            acc[mf][nf] = (f32x4){0.f, 0.f, 0.f, 0.f};

    // prologue: kk=0 tile
    {
        float4 xa = *reinterpret_cast<const float4*>(xrow);
        float4 xb = *reinterpret_cast<const float4*>(xrow + 4);
        *reinterpret_cast<us8*>(xs0 + sr * 72 + sc0) = cvt8(xa, xb);
    }
    us8 wc[3][2];
    #pragma unroll
    for (int mf = 0; mf < 3; ++mf)
        #pragma unroll
        for (int k2 = 0; k2 < 2; ++k2)
            wc[mf][k2] = *reinterpret_cast<const us8*>(wrow[mf] + k2 * 32);
    __syncthreads();

    for (int kk = 0; kk < 16; ++kk) {
        unsigned short* xcur = (kk & 1) ? xs1 : xs0;
        unsigned short* xnxt = (kk & 1) ? xs0 : xs1;
        const bool pf = (kk < 15);
        float4 na, nb;
        us8 wn[3][2];
        if (pf) {
            na = *reinterpret_cast<const float4*>(xrow + (kk + 1) * 64);
            nb = *reinterpret_cast<const float4*>(xrow + (kk + 1) * 64 + 4);
            #pragma unroll
            for (int mf = 0; mf < 3; ++mf)
                #pragma unroll
                for (int k2 = 0; k2 < 2; ++k2)
                    wn[mf][k2] = *reinterpret_cast<const us8*>(wrow[mf] + (kk + 1) * 64 + k2 * 32);
        }
        #pragma unroll
        for (int k2 = 0; k2 < 2; ++k2) {
            bf16x8 bfr[2];
            #pragma unroll
            for (int nf = 0; nf < 2; ++nf)
                bfr[nf] = *reinterpret_cast<const bf16x8*>(xcur + (nf * 16 + l15) * 72 + k2 * 32 + g * 8);
            #pragma unroll
            for (int mf = 0; mf < 3; ++mf) {
                bf16x8 afr = *reinterpret_cast<const bf16x8*>(&wc[mf][k2]);
                #pragma unroll
                for (int nf = 0; nf < 2; ++nf)
                    acc[mf][nf] = __builtin_amdgcn_mfma_f32_16x16x32_bf16(
                        afr, bfr[nf], acc[mf][nf], 0, 0, 0);
            }
        }
        if (pf) {
            *reinterpret_cast<us8*>(xnxt + sr * 72 + sc0) = cvt8(na, nb);
            #pragma unroll
            for (int mf = 0; mf < 3; ++mf)
                #pragma unroll
                for (int k2 = 0; k2 < 2; ++k2)
                    wc[mf][k2] = wn[mf][k2];
        }
        __syncthreads();
    }

    // epilogue: C^T frags -> out_lds[32 m][208 n] bf16 (reuses smem)
    unsigned short* out_lds = smem;
    #pragma unroll
    for (int mf = 0; mf < 3; ++mf) {
        const int Mfr = 3 * w + mf;                    // n = 16*Mfr..
        const float s = (Mfr < 4) ? QSCALE : 1.0f;     // scale q columns (n<64)
        #pragma unroll
        for (int nf = 0; nf < 2; ++nf) {
            union { __bf16 h[4]; us4 v; } u;
            #pragma unroll
            for (int r = 0; r < 4; ++r) u.h[r] = (__bf16)(acc[mf][nf][r] * s);
            *reinterpret_cast<us4*>(out_lds + (nf * 16 + l15) * 208 + Mfr * 16 + 4 * g) = u.v;
        }
    }
    __syncthreads();
    {
        const int r = tid >> 3, c = (tid & 7) * 8;
        const size_t gm = (size_t)(m0 + r);
        *reinterpret_cast<us8*>(qs + gm * 64 + c)  = *reinterpret_cast<const us8*>(out_lds + r * 208 + c);
        *reinterpret_cast<us8*>(ksb + gm * 64 + c) = *reinterpret_cast<const us8*>(out_lds + r * 208 + 64 + c);
    }
    {
        const int d = tid >> 2, j0 = (tid & 3) * 8;
        const int b = m0 >> 12, t0 = m0 & 4095;
        alignas(16) unsigned short tmp[8];
        #pragma unroll
        for (int j = 0; j < 8; ++j) tmp[j] = out_lds[(j0 + j) * 208 + 128 + d];
        *reinterpret_cast<us8*>(vt + (size_t)(b * 64 + d) * T_SEQ + t0 + j0) =
            *reinterpret_cast<const us8*>(tmp);
    }
}

// ---------------- K2: causal flash attention, kv-split, dbuf, 1 barrier -----
// grid (160, 4): blockIdx.x -> (qt, split) via triangular decode; each block
// handles kv-tiles [16s, min(16s+16, qt+1)) and writes unnormalized O + (m,l).
__global__ __launch_bounds__(256) void k_attn(const unsigned short* __restrict__ qs,
                                              const unsigned short* __restrict__ ks,
                                              const unsigned short* __restrict__ vt,
                                              float* __restrict__ Opart,
                                              float* __restrict__ mlw) {
    __shared__ unsigned short kbuf[2][64 * 72];
    __shared__ unsigned short vbuf[2][64 * 72];
    __shared__ unsigned short p_lds[4][16 * 72];
    const int tid = threadIdx.x;
    const int w = tid >> 6, lane = tid & 63;
    const int l15 = lane & 15, g = lane >> 4;
    const int batch = blockIdx.y;
    const int i = blockIdx.x;
    // decode i -> (qt, s): offset(qt=16a+b) = 8a(a+1)+(a+1)b, nsplits = a+1
    const int a = (i < 16) ? 0 : (i < 48) ? 1 : (i < 96) ? 2 : 3;
    const int rem = i - 8 * a * (a + 1);
    const int b = rem / (a + 1);
    const int s = rem - b * (a + 1);
    const int qt = 16 * a + b;
    const int it0 = s * 16;
    const int it1 = min(it0 + 16, qt + 1);
    const int q0 = qt * 64;
    const int qi = q0 + 16 * w + l15;
    const size_t qrow = (size_t)batch * T_SEQ + qi;

    bf16x8 qfrag[2];
    qfrag[0] = *reinterpret_cast<const bf16x8*>(qs + qrow * 64 + g * 8);
    qfrag[1] = *reinterpret_cast<const bf16x8*>(qs + qrow * 64 + 32 + g * 8);

    f32x4 accO[4];
    #pragma unroll
    for (int df = 0; df < 4; ++df) accO[df] = (f32x4){0.f, 0.f, 0.f, 0.f};
    float m_run = -1e30f, l_run = 0.f;

    const int sr = tid >> 2, sc0 = (tid & 3) * 16;
    const unsigned short* kbase = ks + ((size_t)batch * T_SEQ + sr) * 64 + sc0;
    const unsigned short* vbase = vt + ((size_t)batch * 64 + sr) * T_SEQ + sc0;

    // prologue: stage tile it0 into buf 0
    {
        us8 a0 = *reinterpret_cast<const us8*>(kbase + (size_t)it0 * 4096);
        us8 a1 = *reinterpret_cast<const us8*>(kbase + (size_t)it0 * 4096 + 8);
        us8 b0 = *reinterpret_cast<const us8*>(vbase + it0 * 64);
        us8 b1 = *reinterpret_cast<const us8*>(vbase + it0 * 64 + 8);
        unsigned short* kd = &kbuf[0][0] + sr * 72 + sc0;
        unsigned short* vd = &vbuf[0][0] + sr * 72 + sc0;
        *reinterpret_cast<us8*>(kd) = a0; *reinterpret_cast<us8*>(kd + 8) = a1;
        *reinterpret_cast<us8*>(vd) = b0; *reinterpret_cast<us8*>(vd + 8) = b1;
    }
    __syncthreads();

    for (int it = it0; it < it1; ++it) {
        const int cur = (it - it0) & 1;
        const bool pf = (it + 1 < it1);
        us8 n0, n1, n2, n3;
        if (pf) {   // issue next tile's loads early (latency hides under compute)
            n0 = *reinterpret_cast<const us8*>(kbase + (size_t)(it + 1) * 4096);
            n1 = *reinterpret_cast<const us8*>(kbase + (size_t)(it + 1) * 4096 + 8);
            n2 = *reinterpret_cast<const us8*>(vbase + (it + 1) * 64);
            n3 = *reinterpret_cast<const us8*>(vbase + (it + 1) * 64 + 8);
        }
        const unsigned short* kt  = &kbuf[cur][0];
        const unsigned short* vti = &vbuf[cur][0];
        // S^T[k][q] = K * Q^T : lane holds q=l15, k = 64it + 16kf + 4g + r
        f32x4 sfr[4];
        #pragma unroll
        for (int kf = 0; kf < 4; ++kf) sfr[kf] = (f32x4){0.f, 0.f, 0.f, 0.f};
        #pragma unroll
        for (int k2 = 0; k2 < 2; ++k2) {
            #pragma unroll
            for (int kf = 0; kf < 4; ++kf) {
                bf16x8 afr = *reinterpret_cast<const bf16x8*>(kt + (kf * 16 + l15) * 72 + k2 * 32 + g * 8);
                sfr[kf] = __builtin_amdgcn_mfma_f32_16x16x32_bf16(afr, qfrag[k2], sfr[kf], 0, 0, 0);
            }
        }
        if (it == qt) {   // diagonal tile: causal mask
            #pragma unroll
            for (int kf = 0; kf < 4; ++kf) {
                #pragma unroll
                for (int r = 0; r < 4; ++r) {
                    const int kidx = it * 64 + kf * 16 + 4 * g + r;
                    if (kidx > qi) sfr[kf][r] = -1e30f;
                }
            }
        }
        // online softmax (exp2 domain; scale folded into q)
        float mx = -1e30f;
        #pragma unroll
        for (int kf = 0; kf < 4; ++kf)
            #pragma unroll
            for (int r = 0; r < 4; ++r) mx = fmaxf(mx, sfr[kf][r]);
        mx = fmaxf(mx, __shfl_xor(mx, 16, 64));
        mx = fmaxf(mx, __shfl_xor(mx, 32, 64));
        if (!__all(mx <= m_run)) {          // exact defer: skip rescale when no new max
            const float m_new = fmaxf(m_run, mx);
            const float alpha = exp2f(m_run - m_new);
            l_run *= alpha;
            #pragma unroll
            for (int df = 0; df < 4; ++df) accO[df] *= alpha;
            m_run = m_new;
        }
        float psum = 0.f;
        unsigned short* pw = &p_lds[w][0];
        #pragma unroll
        for (int kf = 0; kf < 4; ++kf) {
            union { __bf16 h[4]; us4 v; } up;
            #pragma unroll
            for (int r = 0; r < 4; ++r) {
                const float p = exp2f(sfr[kf][r] - m_run);
                psum += p;
                up.h[r] = (__bf16)p;
            }
            *reinterpret_cast<us4*>(pw + l15 * 72 + kf * 16 + 4 * g) = up.v;
        }
        psum += __shfl_xor(psum, 16, 64);
        psum += __shfl_xor(psum, 32, 64);
        l_run += psum;
        // PV: O^T[d][q] += V^T * P^T (p_lds is per-wave private: no barrier)
        bf16x8 bp0 = *reinterpret_cast<const bf16x8*>(pw + l15 * 72 + g * 8);
        bf16x8 bp1 = *reinterpret_cast<const bf16x8*>(pw + l15 * 72 + 32 + g * 8);
        #pragma unroll
        for (int df = 0; df < 4; ++df) {
            bf16x8 a0 = *reinterpret_cast<const bf16x8*>(vti + (df * 16 + l15) * 72 + g * 8);
            bf16x8 a1 = *reinterpret_cast<const bf16x8*>(vti + (df * 16 + l15) * 72 + 32 + g * 8);
            accO[df] = __builtin_amdgcn_mfma_f32_16x16x32_bf16(a0, bp0, accO[df], 0, 0, 0);
            accO[df] = __builtin_amdgcn_mfma_f32_16x16x32_bf16(a1, bp1, accO[df], 0, 0, 0);
        }
        if (pf) {   // stage next tile into the other buffer
            unsigned short* kd = &kbuf[cur ^ 1][0] + sr * 72 + sc0;
            unsigned short* vd = &vbuf[cur ^ 1][0] + sr * 72 + sc0;
            *reinterpret_cast<us8*>(kd) = n0; *reinterpret_cast<us8*>(kd + 8) = n1;
            *reinterpret_cast<us8*>(vd) = n2; *reinterpret_cast<us8*>(vd + 8) = n3;
        }
        __syncthreads();
    }

    // write unnormalized partial O + (m,l)
    const int pb = batch * 160 + i;
    float* ob = Opart + (size_t)pb * 4096 + (16 * w + l15) * 64;
    #pragma unroll
    for (int df = 0; df < 4; ++df)
        *reinterpret_cast<f32x4*>(ob + 16 * df + 4 * g) = accO[df];
    if (g == 0) {
        float* mlp = mlw + (size_t)pb * 128 + (16 * w + l15) * 2;
        mlp[0] = m_run;
        mlp[1] = l_run;
    }
}

// ---------------- K3: combine kv-split partials ----------------
__global__ __launch_bounds__(256) void k_combine(const float* __restrict__ Opart,
                                                 const float* __restrict__ mlw,
                                                 float* __restrict__ out) {
    const int qt = blockIdx.x, batch = blockIdx.y;
    const int t = threadIdx.x;
    const int r = t >> 2, c = (t & 3) * 16;
    const int a = qt >> 4, b = qt & 15;
    const int nsp = a + 1;
    const int pb0 = batch * 160 + 8 * a * (a + 1) + (a + 1) * b;
    float m_g = -1e30f;
    for (int s = 0; s < nsp; ++s)
        m_g = fmaxf(m_g, mlw[(size_t)(pb0 + s) * 128 + r * 2]);
    float den = 0.f;
    f32x4 num[4];
    #pragma unroll
    for (int j = 0; j < 4; ++j) num[j] = (f32x4){0.f, 0.f, 0.f, 0.f};
    for (int s = 0; s < nsp; ++s) {
        const float* mlp = mlw + (size_t)(pb0 + s) * 128 + r * 2;
        const float wgt = exp2f(mlp[0] - m_g);
        den += wgt * mlp[1];
        const f32x4* op = reinterpret_cast<const f32x4*>(
            Opart + (size_t)(pb0 + s) * 4096 + r * 64 + c);
        #pragma unroll
        for (int j = 0; j < 4; ++j) num[j] += op[j] * wgt;
    }
    const float inv = 1.f / den;
    f32x4* o = reinterpret_cast<f32x4*>(out + ((size_t)batch * T_SEQ + qt * 64 + r) * 64 + c);
    #pragma unroll
    for (int j = 0; j < 4; ++j) o[j] = num[j] * inv;
}

extern "C" void kernel_launch(void* const* d_in, const int* in_sizes, int n_in,
                              void* d_out, int out_size, void* d_ws, size_t ws_size,
                              hipStream_t stream) {
    (void)in_sizes; (void)n_in; (void)out_size; (void)ws_size;
    const float* x  = (const float*)d_in[0];
    const float* Wq = (const float*)d_in[1];
    const float* Wk = (const float*)d_in[2];
    const float* Wv = (const float*)d_in[3];
    float* out = (float*)d_out;
    unsigned short* ws16 = (unsigned short*)d_ws;
    unsigned short* wt_g = ws16;               // 3*64*1024  = 196608 shorts
    unsigned short* qsb  = ws16 + 196608;      // 16384*64   = 1048576
    unsigned short* ksb  = qsb + 1048576;
    unsigned short* vtb  = ksb + 1048576;      // 4*64*4096  = 1048576
    float* Opart = (float*)(vtb + 1048576);    // 640*4096 f32 = 10.5 MB
    float* mlw   = Opart + 640 * 4096;         // 640*128 f32
    k_wtrans <<<dim3(48),      dim3(256), 0, stream>>>(Wq, Wk, Wv, wt_g);
    k_proj   <<<dim3(512),     dim3(256), 0, stream>>>(x, wt_g, qsb, ksb, vtb);
    k_attn   <<<dim3(160, 4),  dim3(256), 0, stream>>>(qsb, ksb, vtb, Opart, mlw);
    k_combine<<<dim3(64, 4),   dim3(256), 0, stream>>>(Opart, mlw, out);
}

// Round 3
// 73.706 us; speedup vs baseline: 1.7714x; 1.0128x over previous
//
#include <hip/hip_runtime.h>

#define T_SEQ 4096
#define C_DIM 1024
#define HD 64

typedef __attribute__((ext_vector_type(8))) __bf16 bf16x8;
typedef __attribute__((ext_vector_type(8))) unsigned short us8;
typedef __attribute__((ext_vector_type(4))) unsigned short us4;
typedef __attribute__((ext_vector_type(4))) float f32x4;

// 0.125 (1/sqrt(64)) * log2(e): fold softmax scale + base-2 conversion into q
#define QSCALE 0.18033688011112042f

__device__ __forceinline__ unsigned short f2bf(float f) {
    union { float f; unsigned u; } x; x.f = f;
    unsigned r = x.u + 0x7FFFu + ((x.u >> 16) & 1u);   // RNE
    return (unsigned short)(r >> 16);
}

__device__ __forceinline__ float bf2f(unsigned short u) {
    union { unsigned u; float f; } x; x.u = ((unsigned)u) << 16;
    return x.f;
}

__device__ __forceinline__ us8 cvt8(float4 a, float4 b) {
    union { __bf16 h[8]; us8 v; } u;
    u.h[0] = (__bf16)a.x; u.h[1] = (__bf16)a.y; u.h[2] = (__bf16)a.z; u.h[3] = (__bf16)a.w;
    u.h[4] = (__bf16)b.x; u.h[5] = (__bf16)b.y; u.h[6] = (__bf16)b.z; u.h[7] = (__bf16)b.w;
    return u.v;
}

// XOR-swizzle on a short-index with 64-short (128 B) rows: spreads the
// stride-128B column pattern across bank quads. Apply to BOTH write and read.
__device__ __forceinline__ int swzs(int idx) {
    return idx ^ ((((idx) >> 6) & 7) << 3);
}

// ---------------- K0: W[1024][64] f32 -> W^T[192][1024] bf16 ----------------
__global__ __launch_bounds__(256) void k_wtrans(const float* __restrict__ Wq,
                                                const float* __restrict__ Wk,
                                                const float* __restrict__ Wv,
                                                unsigned short* __restrict__ wt_g) {
    __shared__ unsigned short tile[64][72];
    const int bx = blockIdx.x;
    const int which = bx >> 4;          // 0..2
    const int k0 = (bx & 15) * 64;
    const float* W = (which == 0) ? Wq : ((which == 1) ? Wk : Wv);
    const int t = threadIdx.x;
    {
        const int r = t >> 2, c0 = (t & 3) * 16;
        const float4* src = reinterpret_cast<const float4*>(W + (k0 + r) * HD + c0);
        #pragma unroll
        for (int i = 0; i < 4; ++i) {
            float4 v = src[i];
            tile[r][c0 + 4 * i + 0] = f2bf(v.x);
            tile[r][c0 + 4 * i + 1] = f2bf(v.y);
            tile[r][c0 + 4 * i + 2] = f2bf(v.z);
            tile[r][c0 + 4 * i + 3] = f2bf(v.w);
        }
    }
    __syncthreads();
    {
        const int n = t >> 2, kc0 = (t & 3) * 16;
        alignas(16) unsigned short o[16];
        #pragma unroll
        for (int i = 0; i < 16; ++i) o[i] = tile[kc0 + i][n];
        unsigned short* dst = wt_g + (size_t)(which * 64 + n) * 1024 + k0 + kc0;
        *reinterpret_cast<us8*>(dst)     = *reinterpret_cast<const us8*>(&o[0]);
        *reinterpret_cast<us8*>(dst + 8) = *reinterpret_cast<const us8*>(&o[8]);
    }
}

// ---------------- K1: q,k,v projections, BM=32, dbuf, 1 barrier/iter --------
// out: qs[16384][64] bf16 (scaled), ks[16384][64] bf16, vt[4][64][4096] bf16
__global__ __launch_bounds__(256) void k_proj(const float* __restrict__ x,
                                              const unsigned short* __restrict__ wt_g,
                                              unsigned short* __restrict__ qs,
                                              unsigned short* __restrict__ ksb,
                                              unsigned short* __restrict__ vt) {
    __shared__ unsigned short smem[6656];        // xs dbuf (2*2304) + out_lds (6656) union
    unsigned short* xs0 = smem;
    unsigned short* xs1 = smem + 2304;
    const int tid = threadIdx.x;
    const int w = tid >> 6, lane = tid & 63;
    const int l15 = lane & 15, g = lane >> 4;
    const int m0 = blockIdx.x * 32;
    const int sr = tid >> 3, sc0 = (tid & 7) * 8;
    const float* xrow = x + (size_t)(m0 + sr) * C_DIM + sc0;
    const unsigned short* wrow[3];
    #pragma unroll
    for (int mf = 0; mf < 3; ++mf)
        wrow[mf] = wt_g + (size_t)((3 * w + mf) * 16 + l15) * C_DIM + g * 8;

    f32x4 acc[3][2];
    #pragma unroll
    for (int mf = 0; mf < 3; ++mf)
        #pragma unroll
        for (int nf = 0; nf < 2; ++nf)
            acc[mf][nf] = (f32x4){0.f, 0.f, 0.f, 0.f};

    // prologue: kk=0 tile
    {
        float4 xa = *reinterpret_cast<const float4*>(xrow);
        float4 xb = *reinterpret_cast<const float4*>(xrow + 4);
        *reinterpret_cast<us8*>(xs0 + sr * 72 + sc0) = cvt8(xa, xb);
    }
    us8 wc[3][2];
    #pragma unroll
    for (int mf = 0; mf < 3; ++mf)
        #pragma unroll
        for (int k2 = 0; k2 < 2; ++k2)
            wc[mf][k2] = *reinterpret_cast<const us8*>(wrow[mf] + k2 * 32);
    __syncthreads();

    for (int kk = 0; kk < 16; ++kk) {
        unsigned short* xcur = (kk & 1) ? xs1 : xs0;
        unsigned short* xnxt = (kk & 1) ? xs0 : xs1;
        const bool pf = (kk < 15);
        float4 na, nb;
        us8 wn[3][2];
        if (pf) {
            na = *reinterpret_cast<const float4*>(xrow + (kk + 1) * 64);
            nb = *reinterpret_cast<const float4*>(xrow + (kk + 1) * 64 + 4);
            #pragma unroll
            for (int mf = 0; mf < 3; ++mf)
                #pragma unroll
                for (int k2 = 0; k2 < 2; ++k2)
                    wn[mf][k2] = *reinterpret_cast<const us8*>(wrow[mf] + (kk + 1) * 64 + k2 * 32);
        }
        #pragma unroll
        for (int k2 = 0; k2 < 2; ++k2) {
            bf16x8 bfr[2];
            #pragma unroll
            for (int nf = 0; nf < 2; ++nf)
                bfr[nf] = *reinterpret_cast<const bf16x8*>(xcur + (nf * 16 + l15) * 72 + k2 * 32 + g * 8);
            #pragma unroll
            for (int mf = 0; mf < 3; ++mf) {
                bf16x8 afr = *reinterpret_cast<const bf16x8*>(&wc[mf][k2]);
                #pragma unroll
                for (int nf = 0; nf < 2; ++nf)
                    acc[mf][nf] = __builtin_amdgcn_mfma_f32_16x16x32_bf16(
                        afr, bfr[nf], acc[mf][nf], 0, 0, 0);
            }
        }
        if (pf) {
            *reinterpret_cast<us8*>(xnxt + sr * 72 + sc0) = cvt8(na, nb);
            #pragma unroll
            for (int mf = 0; mf < 3; ++mf)
                #pragma unroll
                for (int k2 = 0; k2 < 2; ++k2)
                    wc[mf][k2] = wn[mf][k2];
        }
        __syncthreads();
    }

    // epilogue: C^T frags -> out_lds[32 m][208 n] bf16 (reuses smem)
    unsigned short* out_lds = smem;
    #pragma unroll
    for (int mf = 0; mf < 3; ++mf) {
        const int Mfr = 3 * w + mf;                    // n = 16*Mfr..
        const float s = (Mfr < 4) ? QSCALE : 1.0f;     // scale q columns (n<64)
        #pragma unroll
        for (int nf = 0; nf < 2; ++nf) {
            union { __bf16 h[4]; us4 v; } u;
            #pragma unroll
            for (int r = 0; r < 4; ++r) u.h[r] = (__bf16)(acc[mf][nf][r] * s);
            *reinterpret_cast<us4*>(out_lds + (nf * 16 + l15) * 208 + Mfr * 16 + 4 * g) = u.v;
        }
    }
    __syncthreads();
    {
        const int r = tid >> 3, c = (tid & 7) * 8;
        const size_t gm = (size_t)(m0 + r);
        *reinterpret_cast<us8*>(qs + gm * 64 + c)  = *reinterpret_cast<const us8*>(out_lds + r * 208 + c);
        *reinterpret_cast<us8*>(ksb + gm * 64 + c) = *reinterpret_cast<const us8*>(out_lds + r * 208 + 64 + c);
    }
    {
        const int d = tid >> 2, j0 = (tid & 3) * 8;
        const int b = m0 >> 12, t0 = m0 & 4095;
        alignas(16) unsigned short tmp[8];
        #pragma unroll
        for (int j = 0; j < 8; ++j) tmp[j] = out_lds[(j0 + j) * 208 + 128 + d];
        *reinterpret_cast<us8*>(vt + (size_t)(b * 64 + d) * T_SEQ + t0 + j0) =
            *reinterpret_cast<const us8*>(tmp);
    }
}

// ---------------- K2: causal flash attention, kv-split(8), swizzled LDS -----
// grid (288, 4), reversed dispatch (big chunks first). Each block handles
// kv-tiles [8s, min(8s+8, qt+1)); single-chunk q-tiles write out directly,
// multi-chunk write bf16 unnormalized O + (m,l).
__global__ __launch_bounds__(256) void k_attn(const unsigned short* __restrict__ qs,
                                              const unsigned short* __restrict__ ks,
                                              const unsigned short* __restrict__ vt,
                                              unsigned short* __restrict__ Opart,
                                              float* __restrict__ mlw,
                                              float* __restrict__ out) {
    // layout (shorts): kbuf[2][64*64] @0, vbuf[2][64*64] @8192, p[4][16*64] @16384
    __shared__ unsigned short sm[20480];    // 40960 B -> 4 blocks/CU
    const int tid = threadIdx.x;
    const int w = tid >> 6, lane = tid & 63;
    const int l15 = lane & 15, g = lane >> 4;
    const int batch = blockIdx.y;
    const int i = 287 - blockIdx.x;     // big chunks dispatched first
    // decode i -> (qt = 8a+b, split s): offset(qt) = 4a(a+1) + b(a+1)
    const int a = (i < 8) ? 0 : (i < 24) ? 1 : (i < 48) ? 2 : (i < 80) ? 3 :
                  (i < 120) ? 4 : (i < 168) ? 5 : (i < 224) ? 6 : 7;
    const int rem = i - 4 * a * (a + 1);
    const int b = rem / (a + 1);
    const int s = rem - b * (a + 1);
    const int qt = 8 * a + b;
    const int ns = a + 1;
    const int it0 = s * 8;
    const int it1 = min(it0 + 8, qt + 1);
    const int qi = qt * 64 + 16 * w + l15;
    const size_t qrow = (size_t)batch * T_SEQ + qi;

    bf16x8 qfrag[2];
    qfrag[0] = *reinterpret_cast<const bf16x8*>(qs + qrow * 64 + g * 8);
    qfrag[1] = *reinterpret_cast<const bf16x8*>(qs + qrow * 64 + 32 + g * 8);

    f32x4 accO[4];
    #pragma unroll
    for (int df = 0; df < 4; ++df) accO[df] = (f32x4){0.f, 0.f, 0.f, 0.f};
    float m_run = -1e30f, l_run = 0.f;

    const int sr = tid >> 2, sc0 = (tid & 3) * 16;
    const unsigned short* kbase = ks + ((size_t)batch * T_SEQ + sr) * 64 + sc0;
    const unsigned short* vbase = vt + ((size_t)batch * 64 + sr) * T_SEQ + sc0;
    const int pbase = 16384 + w * 1024;

    // prologue: stage tile it0 into buf 0 (swizzled)
    {
        us8 a0 = *reinterpret_cast<const us8*>(kbase + (size_t)it0 * 4096);
        us8 a1 = *reinterpret_cast<const us8*>(kbase + (size_t)it0 * 4096 + 8);
        us8 b0 = *reinterpret_cast<const us8*>(vbase + it0 * 64);
        us8 b1 = *reinterpret_cast<const us8*>(vbase + it0 * 64 + 8);
        const int kd = sr * 64 + sc0, vd = 8192 + sr * 64 + sc0;
        *reinterpret_cast<us8*>(sm + swzs(kd))     = a0;
        *reinterpret_cast<us8*>(sm + swzs(kd + 8)) = a1;
        *reinterpret_cast<us8*>(sm + swzs(vd))     = b0;
        *reinterpret_cast<us8*>(sm + swzs(vd + 8)) = b1;
    }
    __syncthreads();

    for (int it = it0; it < it1; ++it) {
        const int cur = (it - it0) & 1;
        const bool pf = (it + 1 < it1);
        us8 n0, n1, n2, n3;
        if (pf) {   // issue next tile's loads early (latency hides under compute)
            n0 = *reinterpret_cast<const us8*>(kbase + (size_t)(it + 1) * 4096);
            n1 = *reinterpret_cast<const us8*>(kbase + (size_t)(it + 1) * 4096 + 8);
            n2 = *reinterpret_cast<const us8*>(vbase + (it + 1) * 64);
            n3 = *reinterpret_cast<const us8*>(vbase + (it + 1) * 64 + 8);
        }
        const int kb = cur * 4096;
        const int vb = 8192 + cur * 4096;
        // S^T[k][q] = K * Q^T : lane holds q=l15, k = 64it + 16kf + 4g + r
        f32x4 sfr[4];
        #pragma unroll
        for (int kf = 0; kf < 4; ++kf) sfr[kf] = (f32x4){0.f, 0.f, 0.f, 0.f};
        __builtin_amdgcn_s_setprio(1);
        #pragma unroll
        for (int k2 = 0; k2 < 2; ++k2) {
            #pragma unroll
            for (int kf = 0; kf < 4; ++kf) {
                bf16x8 afr = *reinterpret_cast<const bf16x8*>(
                    sm + swzs(kb + (kf * 16 + l15) * 64 + k2 * 32 + g * 8));
                sfr[kf] = __builtin_amdgcn_mfma_f32_16x16x32_bf16(afr, qfrag[k2], sfr[kf], 0, 0, 0);
            }
        }
        __builtin_amdgcn_s_setprio(0);
        if (it == qt) {   // diagonal tile: causal mask
            #pragma unroll
            for (int kf = 0; kf < 4; ++kf) {
                #pragma unroll
                for (int r = 0; r < 4; ++r) {
                    const int kidx = it * 64 + kf * 16 + 4 * g + r;
                    if (kidx > qi) sfr[kf][r] = -1e30f;
                }
            }
        }
        // online softmax (exp2 domain; scale folded into q) — tree max
        float m0 = fmaxf(fmaxf(sfr[0][0], sfr[0][1]), fmaxf(sfr[0][2], sfr[0][3]));
        float m1 = fmaxf(fmaxf(sfr[1][0], sfr[1][1]), fmaxf(sfr[1][2], sfr[1][3]));
        float m2 = fmaxf(fmaxf(sfr[2][0], sfr[2][1]), fmaxf(sfr[2][2], sfr[2][3]));
        float m3 = fmaxf(fmaxf(sfr[3][0], sfr[3][1]), fmaxf(sfr[3][2], sfr[3][3]));
        float mx = fmaxf(fmaxf(m0, m1), fmaxf(m2, m3));
        mx = fmaxf(mx, __shfl_xor(mx, 16, 64));
        mx = fmaxf(mx, __shfl_xor(mx, 32, 64));
        if (!__all(mx <= m_run)) {          // exact defer: skip rescale when no new max
            const float m_new = fmaxf(m_run, mx);
            const float alpha = exp2f(m_run - m_new);
            l_run *= alpha;
            #pragma unroll
            for (int df = 0; df < 4; ++df) accO[df] *= alpha;
            m_run = m_new;
        }
        float psum = 0.f;
        #pragma unroll
        for (int kf = 0; kf < 4; ++kf) {
            union { __bf16 h[4]; us4 v; } up;
            #pragma unroll
            for (int r = 0; r < 4; ++r) {
                const float p = exp2f(sfr[kf][r] - m_run);
                psum += p;
                up.h[r] = (__bf16)p;
            }
            *reinterpret_cast<us4*>(sm + swzs(pbase + l15 * 64 + kf * 16 + 4 * g)) = up.v;
        }
        psum += __shfl_xor(psum, 16, 64);
        psum += __shfl_xor(psum, 32, 64);
        l_run += psum;
        // PV: O^T[d][q] += V^T * P^T (p region is per-wave private: no barrier)
        bf16x8 bp0 = *reinterpret_cast<const bf16x8*>(sm + swzs(pbase + l15 * 64 + g * 8));
        bf16x8 bp1 = *reinterpret_cast<const bf16x8*>(sm + swzs(pbase + l15 * 64 + 32 + g * 8));
        __builtin_amdgcn_s_setprio(1);
        #pragma unroll
        for (int df = 0; df < 4; ++df) {
            bf16x8 a0 = *reinterpret_cast<const bf16x8*>(
                sm + swzs(vb + (df * 16 + l15) * 64 + g * 8));
            bf16x8 a1 = *reinterpret_cast<const bf16x8*>(
                sm + swzs(vb + (df * 16 + l15) * 64 + 32 + g * 8));
            accO[df] = __builtin_amdgcn_mfma_f32_16x16x32_bf16(a0, bp0, accO[df], 0, 0, 0);
            accO[df] = __builtin_amdgcn_mfma_f32_16x16x32_bf16(a1, bp1, accO[df], 0, 0, 0);
        }
        __builtin_amdgcn_s_setprio(0);
        if (pf) {   // stage next tile into the other buffer (swizzled)
            const int kd = (cur ^ 1) * 4096 + sr * 64 + sc0;
            const int vd = 8192 + (cur ^ 1) * 4096 + sr * 64 + sc0;
            *reinterpret_cast<us8*>(sm + swzs(kd))     = n0;
            *reinterpret_cast<us8*>(sm + swzs(kd + 8)) = n1;
            *reinterpret_cast<us8*>(sm + swzs(vd))     = n2;
            *reinterpret_cast<us8*>(sm + swzs(vd + 8)) = n3;
        }
        __syncthreads();
    }

    if (ns == 1) {
        // single chunk: write normalized output directly
        const float inv = 1.0f / l_run;
        #pragma unroll
        for (int df = 0; df < 4; ++df) {
            f32x4 o = accO[df] * inv;
            *reinterpret_cast<f32x4*>(out + qrow * 64 + df * 16 + 4 * g) = o;
        }
    } else {
        // write unnormalized bf16 partial O + (m,l)
        const int pb = batch * 288 + i;
        unsigned short* ob = Opart + (size_t)pb * 4096 + (16 * w + l15) * 64;
        #pragma unroll
        for (int df = 0; df < 4; ++df) {
            union { __bf16 h[4]; us4 v; } u;
            #pragma unroll
            for (int r = 0; r < 4; ++r) u.h[r] = (__bf16)accO[df][r];
            *reinterpret_cast<us4*>(ob + 16 * df + 4 * g) = u.v;
        }
        if (g == 0) {
            float* mlp = mlw + (size_t)pb * 128 + (16 * w + l15) * 2;
            mlp[0] = m_run;
            mlp[1] = l_run;
        }
    }
}

// ---------------- K3: combine kv-split partials (qt >= 8 only) --------------
__global__ __launch_bounds__(256) void k_combine(const unsigned short* __restrict__ Opart,
                                                 const float* __restrict__ mlw,
                                                 float* __restrict__ out) {
    const int qt = 8 + blockIdx.x, batch = blockIdx.y;
    const int t = threadIdx.x;
    const int r = t >> 2, c = (t & 3) * 16;
    const int a = qt >> 3;
    const int nsp = a + 1;
    const int pb0 = batch * 288 + 4 * a * (a + 1) + (qt & 7) * (a + 1);
    float m_g = -1e30f;
    for (int s = 0; s < nsp; ++s)
        m_g = fmaxf(m_g, mlw[(size_t)(pb0 + s) * 128 + r * 2]);
    float den = 0.f;
    f32x4 num[4];
    #pragma unroll
    for (int j = 0; j < 4; ++j) num[j] = (f32x4){0.f, 0.f, 0.f, 0.f};
    for (int s = 0; s < nsp; ++s) {
        const float* mlp = mlw + (size_t)(pb0 + s) * 128 + r * 2;
        const float wgt = exp2f(mlp[0] - m_g);
        den += wgt * mlp[1];
        const unsigned short* op = Opart + (size_t)(pb0 + s) * 4096 + r * 64 + c;
        us8 v0 = *reinterpret_cast<const us8*>(op);
        us8 v1 = *reinterpret_cast<const us8*>(op + 8);
        #pragma unroll
        for (int j = 0; j < 8; ++j) {
            num[j >> 2][j & 3] += wgt * bf2f(v0[j]);
            num[2 + (j >> 2)][j & 3] += wgt * bf2f(v1[j]);
        }
    }
    const float inv = 1.f / den;
    f32x4* o = reinterpret_cast<f32x4*>(out + ((size_t)batch * T_SEQ + qt * 64 + r) * 64 + c);
    #pragma unroll
    for (int j = 0; j < 4; ++j) o[j] = num[j] * inv;
}

extern "C" void kernel_launch(void* const* d_in, const int* in_sizes, int n_in,
                              void* d_out, int out_size, void* d_ws, size_t ws_size,
                              hipStream_t stream) {
    (void)in_sizes; (void)n_in; (void)out_size; (void)ws_size;
    const float* x  = (const float*)d_in[0];
    const float* Wq = (const float*)d_in[1];
    const float* Wk = (const float*)d_in[2];
    const float* Wv = (const float*)d_in[3];
    float* out = (float*)d_out;
    unsigned short* ws16 = (unsigned short*)d_ws;
    unsigned short* wt_g = ws16;               // 3*64*1024  = 196608 shorts
    unsigned short* qsb  = ws16 + 196608;      // 16384*64   = 1048576
    unsigned short* ksb  = qsb + 1048576;
    unsigned short* vtb  = ksb + 1048576;      // 4*64*4096  = 1048576
    unsigned short* Opart = vtb + 1048576;     // 4*288*4096 bf16 = 9.4 MB
    float* mlw = (float*)(Opart + 4718592);    // 4*288*128 f32
    k_wtrans <<<dim3(48),      dim3(256), 0, stream>>>(Wq, Wk, Wv, wt_g);
    k_proj   <<<dim3(512),     dim3(256), 0, stream>>>(x, wt_g, qsb, ksb, vtb);
    k_attn   <<<dim3(288, 4),  dim3(256), 0, stream>>>(qsb, ksb, vtb, Opart, mlw, out);
    k_combine<<<dim3(56, 4),   dim3(256), 0, stream>>>(Opart, mlw, out);
}